// Round 14
// baseline (40.897 us; speedup 1.0000x reference)
//
#include <hip/hip_runtime.h>
#include <math.h>

namespace {

constexpr int IMG  = 128;
constexpr int NPIX = IMG * IMG;
constexpr int B    = 4;
constexpr int V    = 600;
constexpr int F    = 1000;
constexpr int FP   = 1024;          // padded/sorted face slots (16 chunks x 64)
constexpr float FOCALF = 1.5f;
constexpr float EPSF   = 1e-8f;
constexpr float SLACK  = 1e-5f;     // >> max rounding error of w (~3e-6)
constexpr float ZEPS    = 1e-4f;    // zt-window margin (round-12-proven)
constexpr float DENSAFE = 1e-3f;
constexpr float ZMARGIN = 0.03f;    // z >= minz - max(ZMARGIN, 0.011*minz)

struct FaceRec {
    float e0x, e0y, bx, by;   // edge for w0 (v1->v2), base b
    float e1x, e1y, cx, cy;   // edge for w1 (v2->v0), base c
    float e2x, e2y, ax, ay;   // edge for w2 (v0->v1), base a
    float den, z0, z1, z2;
};

// Exact reference projection + edge setup (identical rounding in all users).
__device__ inline FaceRec project_face(const float* __restrict__ vb,
                                       const int* __restrict__ faces, int f) {
#pragma clang fp contract(off)
    FaceRec r;
    int i0 = faces[f * 3 + 0], i1 = faces[f * 3 + 1], i2 = faces[f * 3 + 2];
    float x0 = vb[i0 * 3], y0 = vb[i0 * 3 + 1]; r.z0 = vb[i0 * 3 + 2];
    float x1 = vb[i1 * 3], y1 = vb[i1 * 3 + 1]; r.z1 = vb[i1 * 3 + 2];
    float x2 = vb[i2 * 3], y2 = vb[i2 * 3 + 1]; r.z2 = vb[i2 * 3 + 2];
    r.ax = (FOCALF * x0) / r.z0; r.ay = (FOCALF * y0) / r.z0;
    r.bx = (FOCALF * x1) / r.z1; r.by = (FOCALF * y1) / r.z1;
    r.cx = (FOCALF * x2) / r.z2; r.cy = (FOCALF * y2) / r.z2;
    r.e0x = r.cx - r.bx; r.e0y = r.cy - r.by;
    r.e1x = r.ax - r.cx; r.e1y = r.ay - r.cy;
    r.e2x = r.bx - r.ax; r.e2y = r.by - r.ay;
    float den = r.e2x * (r.cy - r.ay) - r.e2y * (r.cx - r.ax); // == ref area
    if (!(fabsf(den) > EPSF)) den = 0.0f;
    r.den = den;
    return r;
}

__device__ inline float seg_dist2(float px, float py, float ax, float ay,
                                  float bx, float by) {
#pragma clang fp contract(off)
    float ex = bx - ax, ey = by - ay;
    float dx = px - ax, dy = py - ay;
    float ee = fmaxf(ex * ex + ey * ey, EPSF);
    float t  = (dx * ex + dy * ey) / ee;
    t = fminf(fmaxf(t, 0.0f), 1.0f);
    float rx = dx - t * ex;
    float ry = dy - t * ey;
    return rx * rx + ry * ry;
}

// prep: one block per image. Clears zbest, counting-sorts faces into 64
// z-buckets by minz (order within bucket arbitrary — merge is order-free),
// writes 24-float records in sorted order, rank[] (orig id -> position), and
// the suffix-min of tskip over the ACTUAL final order (so any ordering bug
// costs speed, never correctness). Record layout [pos][24]:
//  0-3: e0x e0y bx by | 4-7: e1x e1y cx cy | 8-11: e2x e2y ax ay
//  12-15: den azr bzr czr | 16-19: az bz cz idbits | 20-23: suffmin sliver 0 0
__global__ __launch_bounds__(1024) void prep(const float* __restrict__ verts,
                                             const int* __restrict__ faces,
                                             float* __restrict__ fdata,
                                             int* __restrict__ rank,
                                             unsigned long long* __restrict__ zbest) {
#pragma clang fp contract(off)
    __shared__ int   hist[64];
    __shared__ int   sortedid[FP];
    __shared__ float stmp[FP];
    const int tid = threadIdx.x;
    const int b   = blockIdx.x;
    const float* vb = verts + (size_t)b * V * 3;

    // clear this image's zbest (stores complete in background)
    for (int i = tid; i < NPIX; i += FP) zbest[b * NPIX + i] = ~0ULL;

    if (tid < 64) hist[tid] = 0;
    sortedid[tid] = -1;
    __syncthreads();

    // pass 1: bucket by minz (z in [1,3) by construction; clamped anyway)
    int mybucket = -1;
    if (tid < F) {
        FaceRec r = project_face(vb, faces, tid);
        if (r.den != 0.0f) {
            float minz = fminf(fminf(r.z0, r.z1), r.z2);
            mybucket = min(63, max(0, (int)((minz - 1.0f) * 32.0f)));
            atomicAdd(&hist[mybucket], 1);
        }
    }
    __syncthreads();
    if (tid == 0) {            // exclusive prefix over 64 buckets
        int acc = 0;
        for (int i = 0; i < 64; ++i) { int h = hist[i]; hist[i] = acc; acc += h; }
    }
    __syncthreads();
    if (mybucket >= 0) {
        int pos = atomicAdd(&hist[mybucket], 1);
        sortedid[pos] = tid;
    }
    __syncthreads();

    // pass 2: build record at sorted position tid
    const int id   = sortedid[tid];
    const bool real = (id >= 0);
    FaceRec r = {};
    float azr = 0.0f, bzr = 0.0f, czr = 0.0f;
    float tsk = INFINITY;      // suffix input: +INF for pads AND slivers
    bool sliver = false;
    if (real) {
        r = project_face(vb, faces, id);   // same code -> identical rounding
        const float rd = __builtin_amdgcn_rcpf(r.den);
        azr = r.z0 * rd; bzr = r.z1 * rd; czr = r.z2 * rd;
        float minz = fminf(fminf(r.z0, r.z1), r.z2);
        sliver = fabsf(r.den) < DENSAFE;   // r.den != 0 for real faces
        if (!sliver) tsk = minz - fmaxf(ZMARGIN, 0.011f * minz);
    }
    stmp[tid] = tsk;
    __syncthreads();
    // suffix-min over actual order (log steps, window doubling)
    float v = stmp[tid];
    for (int off = 1; off < FP; off <<= 1) {
        float o = (tid + off < FP) ? stmp[tid + off] : INFINITY;
        __syncthreads();
        v = fminf(v, o);
        stmp[tid] = v;
        __syncthreads();
    }

    float* o = fdata + (size_t)(b * FP + tid) * 24;
    o[0]  = r.e0x; o[1]  = r.e0y; o[2]  = r.bx;  o[3]  = r.by;
    o[4]  = r.e1x; o[5]  = r.e1y; o[6]  = r.cx;  o[7]  = r.cy;
    o[8]  = r.e2x; o[9]  = r.e2y; o[10] = r.ax;  o[11] = r.ay;
    o[12] = r.den; o[13] = azr;   o[14] = bzr;   o[15] = czr;
    o[16] = r.z0;  o[17] = r.z1;  o[18] = r.z2;
    o[19] = __int_as_float(real ? id : 0);
    o[20] = v;                       // suffmin of tskip over positions >= tid
    o[21] = sliver ? 1.0f : 0.0f;
    o[22] = 0.0f; o[23] = 0.0f;
    if (real) rank[b * F + id] = tid;
}

// Fused bin+shade. 1024 blocks x 512 thr (8 waves). Block = (ch, b, slice):
// one z-sorted 64-face chunk x 16 tiles (4x4 lattice). Waves pull tiles off
// an LDS ticket. Per tile: item skip if all remaining-z provably lose, else
// register bin test -> mask walk in ascending-z order with suffix-min breaks;
// zt-window prunes the exact path. All skips are strict-loss-proven; the
// merge is an order-free packed-u64 atomicMin -> output bit-identical.
__global__ __launch_bounds__(512, 8) void rast(const float* __restrict__ fdata,
                                               unsigned long long* __restrict__ zbest) {
#pragma clang fp contract(off)
    __shared__ float4 sface[64 * 6];     // 6 KB: this block's chunk
    __shared__ unsigned int lticket;
    const int tid  = threadIdx.x;
    const int lane = tid & 63;
    const int bk   = blockIdx.x;
    const int ch   = bk & 15;          // z-sorted face chunk
    const int b    = (bk >> 4) & 3;    // image
    const int slice = bk >> 6;         // 0..15 -> 4x4 lattice phase
    if (tid == 0) lticket = 0u;

    // pin this chunk's face data: one face per lane
    const int f0 = ch * 64;
    const float4* fd4 = (const float4*)(fdata + (size_t)(b * FP + f0 + lane) * 24);
    const float4 q0 = fd4[0], q1 = fd4[1], q2 = fd4[2], q3 = fd4[3],
                 q4 = fd4[4], q5 = fd4[5];
    if (tid < 64) {                     // wave 0 stages for all 8 waves
        sface[tid * 6 + 0] = q0; sface[tid * 6 + 1] = q1;
        sface[tid * 6 + 2] = q2; sface[tid * 6 + 3] = q3;
        sface[tid * 6 + 4] = q4; sface[tid * 6 + 5] = q5;
    }
    const unsigned long long slivmask = __ballot(q5.y != 0.0f); // per-chunk
    __syncthreads();
    const float minskip = sface[5].x;   // suffmin at chunk start (pos f0)

    const bool valid = (q3.x != 0.0f);  // pads/degens have den==0
    const float s = q3.x > 0.0f ? 1.0f : -1.0f;
    const float g0x = s * q0.x, g0y = s * q0.y;
    const float g1x = s * q1.x, g1y = s * q1.y;
    const float g2x = s * q2.x, g2y = s * q2.y;
    const bool c0y = g0x >= 0.0f, c0x = g0y >= 0.0f;
    const bool c1y = g1x >= 0.0f, c1x = g1y >= 0.0f;
    const bool c2y = g2x >= 0.0f, c2x = g2y >= 0.0f;

    const int dpx = lane & 7, dpy = lane >> 3;

    for (;;) {
        unsigned int j = 0;
        if (lane == 0) j = atomicAdd(&lticket, 1u);
        j = (unsigned int)__shfl((int)j, 0);
        if (j >= 16u) break;
        const unsigned int jj = (j + (unsigned int)ch) & 15u;  // stagger

        const int row = (slice >> 2) + 4 * (int)(jj >> 2);
        const int col = (slice & 3) + 4 * (int)(jj & 3);
        const int ix0 = col * 8, iy0 = row * 8;
        const int ix  = ix0 + dpx, iy = iy0 + dpy;
        const float px = 1.0f - (2.0f * (float)ix + 1.0f) / (float)IMG;
        const float py = 1.0f - (2.0f * (float)iy + 1.0f) / (float)IMG;
        const float pxmax = 1.0f - (2.0f * (float)ix0 + 1.0f) / (float)IMG;
        const float pxmin = 1.0f - (2.0f * (float)(ix0 + 7) + 1.0f) / (float)IMG;
        const float pymax = 1.0f - (2.0f * (float)iy0 + 1.0f) / (float)IMG;
        const float pymin = 1.0f - (2.0f * (float)(iy0 + 7) + 1.0f) / (float)IMG;

        const int gp = b * NPIX + iy * IMG + ix;
        const unsigned ztop = (unsigned)(zbest[gp] >> 32);
        float zbf  = (ztop == 0xFFFFFFFFu) ? INFINITY : __uint_as_float(ztop);
        float zbfp = zbf + ZEPS;

        // item-level skip: every non-sliver face in [f0,FP) has z > zbf at
        // every lane (strict: z >= tskip >= suffmin > zbf). Fast path when
        // the chunk has no slivers.
        const bool itemdead = __all(minskip > zbf);
        if (itemdead & (slivmask == 0ULL)) continue;

        // conservative half-plane bin test (max over tile rect >= -SLACK)
        bool pass = valid;
        pass &= (g0x * ((c0y ? pymax : pymin) - q0.w)
               - g0y * ((c0x ? pxmin : pxmax) - q0.z)) >= -SLACK;
        pass &= (g1x * ((c1y ? pymax : pymin) - q1.w)
               - g1y * ((c1x ? pxmin : pxmax) - q1.z)) >= -SLACK;
        pass &= (g2x * ((c2y ? pymax : pymin) - q2.w)
               - g2y * ((c2x ? pxmin : pxmax) - q2.z)) >= -SLACK;

        unsigned long long pmin = ~0ULL;
        unsigned long long mask = __ballot(pass);
        bool checks = true;
        if (itemdead) { mask &= slivmask; checks = false; }

        while (mask) {
            const int sl = __builtin_ctzll(mask);
            const unsigned long long bit = mask & (unsigned long long)(-(long long)mask);
            mask &= mask - 1;
            if (checks) {
                // ascending-z walk: suffmin covers positions >= f0+sl.
                const float suffm = sface[sl * 6 + 5].x;
                if (__all(suffm > zbf)) {
                    // all remaining NON-sliver faces strictly lose everywhere
                    mask = (mask | bit) & slivmask;
                    checks = false;
                    continue;
                }
            }
            const float4 r0 = sface[sl * 6 + 0];
            const float4 r1 = sface[sl * 6 + 1];
            const float4 r2 = sface[sl * 6 + 2];
            const float4 r3 = sface[sl * 6 + 3];   // den, azr, bzr, czr
            const float den = r3.x;
            // exact reference edge functions
            float w0 = r0.x * (py - r0.w) - r0.y * (px - r0.z);
            float w1 = r1.x * (py - r1.w) - r1.y * (px - r1.z);
            float w2 = r2.x * (py - r2.w) - r2.y * (px - r2.z);

            // conservative inside: !(w*den < 0) covers w==+-0 and sign-match
            const bool insd = !(w0 * den < 0.0f) & !(w1 * den < 0.0f) &
                              !(w2 * den < 0.0f);
            if (!__any(insd)) continue;

            // cheap z~ via precomputed az*rcp(den) etc.
            const float zt = w0 * r3.y + w1 * r3.z + w2 * r3.w;
            const bool densmall = fabsf(den) < DENSAFE;    // bound invalid
            const bool need = insd & (densmall | ((zt < zbfp) & (zt > -ZEPS)));
            if (__any(need)) {
                // ---- bit-exact reference path ----
                const unsigned ds = __float_as_uint(den) >> 31;
                const bool in0 = (w0 == 0.0f) | ((__float_as_uint(w0) >> 31) == ds);
                const bool in1 = (w1 == 0.0f) | ((__float_as_uint(w1) >> 31) == ds);
                const bool in2 = (w2 == 0.0f) | ((__float_as_uint(w2) >> 31) == ds);
                if (in0 & in1 & in2) {
                    const float4 r4 = sface[sl * 6 + 4];   // az, bz, cz, idbits
                    float s0 = w0 / den, s1 = w1 / den, s2 = w2 / den;
                    float z  = s0 * r4.x + s1 * r4.y + s2 * r4.z;
                    if (z > 0.0f) {
                        const unsigned fj = __float_as_uint(r4.w); // orig id
                        unsigned long long pk =
                            ((unsigned long long)__float_as_uint(z) << 32) | fj;
                        pmin = pmin < pk ? pmin : pk;
                        zbf  = fminf(zbf, z);
                        zbfp = zbf + ZEPS;
                    }
                }
            }
        }
        if (pmin != ~0ULL) atomicMin(&zbest[gp], pmin);
    }
}

// Unpack winner; recompute bary + dists from the sorted record via rank[].
__global__ __launch_bounds__(256) void pass2(const float* __restrict__ fdata,
                                             const int* __restrict__ rank,
                                             const unsigned long long* __restrict__ zbest,
                                             float* __restrict__ out) {
#pragma clang fp contract(off)
    const int gp = blockIdx.x * 256 + threadIdx.x;
    const int b  = gp >> 14;
    const int p  = gp & (NPIX - 1);
    const int ix = p & (IMG - 1), iy = p >> 7;

    unsigned long long packed = zbest[gp];
    float o_face = -1.0f, o_z = -1.0f, o_b0 = -1.0f, o_b1 = -1.0f,
          o_b2 = -1.0f, o_d = -1.0f;

    if (packed != ~0ULL) {
        const int   idx = (int)(unsigned)(packed & 0xffffffffu);
        const float z   = __uint_as_float((unsigned)(packed >> 32));
        const float px  = 1.0f - (2.0f * (float)ix + 1.0f) / (float)IMG;
        const float py  = 1.0f - (2.0f * (float)iy + 1.0f) / (float)IMG;

        const int pos = rank[b * F + idx];
        const float4* fd4 = (const float4*)(fdata + (size_t)(b * FP + pos) * 24);
        float4 q0 = fd4[0], q1 = fd4[1], q2 = fd4[2], q3 = fd4[3];
        float den = q3.x;
        float w0 = q0.x * (py - q0.w) - q0.y * (px - q0.z);
        float w1 = q1.x * (py - q1.w) - q1.y * (px - q1.z);
        float w2 = q2.x * (py - q2.w) - q2.y * (px - q2.z);
        float s0 = w0 / den, s1 = w1 / den, s2 = w2 / den;

        // a=(q2.z,q2.w)  b=(q0.z,q0.w)  c=(q1.z,q1.w): reference-rounded coords
        float d2 = fminf(fminf(seg_dist2(px, py, q2.z, q2.w, q0.z, q0.w),
                               seg_dist2(px, py, q0.z, q0.w, q1.z, q1.w)),
                         seg_dist2(px, py, q1.z, q1.w, q2.z, q2.w));
        o_face = (float)idx; o_z = z;
        o_b0 = s0; o_b1 = s1; o_b2 = s2;
        o_d = -d2;
    }

    out[gp]            = o_face;
    out[B * NPIX + gp] = o_z;
    const int bary_base = 2 * B * NPIX;
    out[bary_base + gp * 3 + 0] = o_b0;
    out[bary_base + gp * 3 + 1] = o_b1;
    out[bary_base + gp * 3 + 2] = o_b2;
    out[5 * B * NPIX + gp] = o_d;
}

} // namespace

extern "C" void kernel_launch(void* const* d_in, const int* in_sizes, int n_in,
                              void* d_out, int out_size, void* d_ws, size_t ws_size,
                              hipStream_t stream) {
    const float* verts = (const float*)d_in[0];  // (B,V,3) f32
    const int*   faces = (const int*)d_in[1];    // (F,3) i32
    float* out = (float*)d_out;

    // ws layout: zbest 512KB | fdata B*FP*96B = 384KB | rank 16KB
    char* ws = (char*)d_ws;
    unsigned long long* zbest = (unsigned long long*)ws;
    float* fdata = (float*)(ws + (size_t)B * NPIX * 8);
    int*   rank  = (int*)(ws + (size_t)B * NPIX * 8 + (size_t)B * FP * 96);

    prep<<<B, 1024, 0, stream>>>(verts, faces, fdata, rank, zbest);
    rast<<<1024, 512, 0, stream>>>(fdata, zbest);
    pass2<<<B * NPIX / 256, 256, 0, stream>>>(fdata, rank, zbest, out);
}

// Round 15
// 31.420 us; speedup vs baseline: 1.3016x; 1.3016x over previous
//
#include <hip/hip_runtime.h>
#include <math.h>

namespace {

constexpr int IMG  = 128;
constexpr int NPIX = IMG * IMG;
constexpr int B    = 4;
constexpr int V    = 600;
constexpr int F    = 1000;
constexpr int FP   = 1024;          // padded face slots (16 chunks x 64)
constexpr float FOCALF = 1.5f;
constexpr float EPSF   = 1e-8f;
// affine-filter margins (error bounds derived in journal, >=4x slack):
constexpr float EW   = 1e-4f;       // |g~ - g_ref| <= ~2.5e-5
constexpr float EBIN = 2e-4f;       // corner-eval slack for bin test
constexpr float DENSAFE = 1e-3f;    // below this -> eps=INF (always exact)

__device__ inline float seg_dist2(float px, float py, float ax, float ay,
                                  float bx, float by) {
#pragma clang fp contract(off)
    float ex = bx - ax, ey = by - ay;
    float dx = px - ax, dy = py - ay;
    float ee = fmaxf(ex * ex + ey * ey, EPSF);
    float t  = (dx * ex + dy * ey) / ee;
    t = fminf(fmaxf(t, 0.0f), 1.0f);
    float rx = dx - t * ex;
    float ry = dy - t * ey;
    return rx * rx + ry * ry;
}

// facedata layout [b][fp][28] (7 x float4, 112B):
//  [0-3]:  a0s b0s c0s sden   (sign-folded edge-0 affine coeffs; sden=|den|)
//  [4-7]:  a1s b1s c1s eps    (edge-1; eps = z-window margin, INF for slivers)
//  [8-11]: Zx  Zy  Zc  0      (affine z~ coeffs, rcp(den)-folded)
//  [12-15]: e0x e0y bx by  | [16-19]: e1x e1y cx cy | [20-23]: e2x e2y ax ay
//  [24-27]: den az bz cz      (exact-path data, reference-rounded)
// Dead slots (pad/degenerate): c0s=-1e30 -> never passes bin or cheap test.
__global__ __launch_bounds__(256) void setup_clear(const float* __restrict__ verts,
                                                   const int* __restrict__ faces,
                                                   float* __restrict__ fdata,
                                                   unsigned long long* __restrict__ zbest) {
#pragma clang fp contract(off)
    int t = blockIdx.x * 256 + threadIdx.x;   // grid covers B*NPIX = 65536
    zbest[t] = ~0ULL;
    if (t >= B * FP) return;
    const int b = t >> 10, fp = t & (FP - 1);
    float* o = fdata + (size_t)t * 28;
    bool dead = (fp >= F);
    float e0x=0,e0y=0,bx=0,by=0,e1x=0,e1y=0,cx=0,cy=0,e2x=0,e2y=0,ax=0,ay=0;
    float den=0, z0=0, z1=0, z2=0;
    if (!dead) {
        int i0 = faces[fp * 3 + 0], i1 = faces[fp * 3 + 1], i2 = faces[fp * 3 + 2];
        const float* vb = verts + (size_t)b * V * 3;
        float x0 = vb[i0 * 3], y0 = vb[i0 * 3 + 1]; z0 = vb[i0 * 3 + 2];
        float x1 = vb[i1 * 3], y1 = vb[i1 * 3 + 1]; z1 = vb[i1 * 3 + 2];
        float x2 = vb[i2 * 3], y2 = vb[i2 * 3 + 1]; z2 = vb[i2 * 3 + 2];
        // exact reference projection + edge rounding
        ax = (FOCALF * x0) / z0; ay = (FOCALF * y0) / z0;
        bx = (FOCALF * x1) / z1; by = (FOCALF * y1) / z1;
        cx = (FOCALF * x2) / z2; cy = (FOCALF * y2) / z2;
        e0x = cx - bx; e0y = cy - by;
        e1x = ax - cx; e1y = ay - cy;
        e2x = bx - ax; e2y = by - ay;
        den = e2x * (cy - ay) - e2y * (cx - ax);   // == reference area tree
        if (!(fabsf(den) > EPSF)) { den = 0.0f; dead = true; }
    }
    if (dead) {
        o[0] = 0.0f; o[1] = 0.0f; o[2] = -1e30f; o[3] = 0.0f;
        #pragma unroll
        for (int k = 4; k < 28; ++k) o[k] = 0.0f;
        return;
    }
    // affine edge coeffs: w_i = a_i*px + b_i*py + c_i
    float a0 = -e0y, b0 = e0x, c0 = e0y * bx - e0x * by;
    float a1 = -e1y, b1 = e1x, c1 = e1y * cx - e1x * cy;
    float a2 = -e2y, b2 = e2x, c2 = e2y * ax - e2x * ay;
    const float s  = den > 0.0f ? 1.0f : -1.0f;
    const float rd = __builtin_amdgcn_rcpf(den);
    const float azr = z0 * rd, bzr = z1 * rd, czr = z2 * rd;
    const float Zx = a0 * azr + a1 * bzr + a2 * czr;
    const float Zy = b0 * azr + b1 * bzr + b2 * czr;
    const float Zc = c0 * azr + c1 * bzr + c2 * czr;
    // abs-sum for the z~ error bound (cancellation-safe)
    const float S = (fabsf(a0) + fabsf(b0) + fabsf(c0)) * fabsf(azr)
                  + (fabsf(a1) + fabsf(b1) + fabsf(c1)) * fabsf(bzr)
                  + (fabsf(a2) + fabsf(b2) + fabsf(c2)) * fabsf(czr);
    const float eps = (fabsf(den) < DENSAFE) ? INFINITY : (1e-4f + 2e-6f * S);
    o[0]  = s * a0; o[1]  = s * b0; o[2]  = s * c0; o[3]  = s * den;  // sden=|den|
    o[4]  = s * a1; o[5]  = s * b1; o[6]  = s * c1; o[7]  = eps;
    o[8]  = Zx;     o[9]  = Zy;     o[10] = Zc;     o[11] = 0.0f;
    o[12] = e0x;    o[13] = e0y;    o[14] = bx;     o[15] = by;
    o[16] = e1x;    o[17] = e1y;    o[18] = cx;     o[19] = cy;
    o[20] = e2x;    o[21] = e2y;    o[22] = ax;     o[23] = ay;
    o[24] = den;    o[25] = z0;     o[26] = z1;     o[27] = z2;
}

// Fused bin+shade. 1024 blocks x 512 thr (8 waves). Block = (ch, b, slice):
// one 64-face chunk x 16 tiles (4x4 lattice); waves pull tiles off an LDS
// ticket. Bin test from per-lane pinned affine coeffs. Survivor loop: 2 LDS
// float4 -> affine g0,g1 + identity g2 (=|den|-g0-g1); z~ window from a 3rd
// float4 only when maybe-inside. Exact reference path (bit-identical to the
// passing round-12 kernel) only when some lane might improve its bound.
__global__ __launch_bounds__(512, 8) void rast(const float* __restrict__ fdata,
                                               unsigned long long* __restrict__ zbest) {
#pragma clang fp contract(off)
    __shared__ float4 sface[64 * 7];     // 7 KB: this block's chunk
    __shared__ unsigned int lticket;
    const int tid  = threadIdx.x;
    const int lane = tid & 63;
    const int bk   = blockIdx.x;
    const int ch   = bk & 15;          // face chunk
    const int b    = (bk >> 4) & 3;    // image
    const int slice = bk >> 6;         // 0..15 -> 4x4 lattice phase
    if (tid == 0) lticket = 0u;

    const int f0 = ch * 64;
    // flat cooperative stage: chunk is 448 contiguous float4s
    const float4* gflat = (const float4*)(fdata + (size_t)(b * FP + f0) * 28);
    if (tid < 448) ((float4*)sface)[tid] = gflat[tid];

    // pin own face's affine coeffs for the bin test
    const float4* fd4 = (const float4*)(fdata + (size_t)(b * FP + f0 + lane) * 28);
    const float4 m0 = fd4[0], m1 = fd4[1];
    // edge 2 via identity: a2s=-(a0s+a1s), b2s=-(b0s+b1s), c2s=sden-c0s-c1s
    const float a2s = -(m0.x + m1.x);
    const float b2s = -(m0.y + m1.y);
    const float c2s = m0.w - m0.z - m1.z;
    const bool c0x = m0.x >= 0.0f, c0y = m0.y >= 0.0f;
    const bool c1x = m1.x >= 0.0f, c1y = m1.y >= 0.0f;
    const bool c2x = a2s >= 0.0f, c2y = b2s >= 0.0f;
    __syncthreads();

    const int dpx = lane & 7, dpy = lane >> 3;

    for (;;) {
        unsigned int j = 0;
        if (lane == 0) j = atomicAdd(&lticket, 1u);
        j = (unsigned int)__shfl((int)j, 0);
        if (j >= 16u) break;
        const unsigned int jj = (j + (unsigned int)ch) & 15u;  // stagger

        const int row = (slice >> 2) + 4 * (int)(jj >> 2);
        const int col = (slice & 3) + 4 * (int)(jj & 3);
        const int ix0 = col * 8, iy0 = row * 8;
        const int ix  = ix0 + dpx, iy = iy0 + dpy;
        const float px = 1.0f - (2.0f * (float)ix + 1.0f) / (float)IMG;
        const float py = 1.0f - (2.0f * (float)iy + 1.0f) / (float)IMG;
        const float pxmax = 1.0f - (2.0f * (float)ix0 + 1.0f) / (float)IMG;
        const float pxmin = 1.0f - (2.0f * (float)(ix0 + 7) + 1.0f) / (float)IMG;
        const float pymax = 1.0f - (2.0f * (float)iy0 + 1.0f) / (float)IMG;
        const float pymin = 1.0f - (2.0f * (float)(iy0 + 7) + 1.0f) / (float)IMG;

        const int gp = b * NPIX + iy * IMG + ix;
        const unsigned ztop = (unsigned)(zbest[gp] >> 32);
        float zbf = (ztop == 0xFFFFFFFFu) ? INFINITY : __uint_as_float(ztop);

        // bin test: max over tile rect of each affine edge >= -EBIN
        bool pass =
            (m0.x * (c0x ? pxmax : pxmin) + m0.y * (c0y ? pymax : pymin) + m0.z)
                >= -EBIN;
        pass &=
            (m1.x * (c1x ? pxmax : pxmin) + m1.y * (c1y ? pymax : pymin) + m1.z)
                >= -EBIN;
        pass &=
            (a2s * (c2x ? pxmax : pxmin) + b2s * (c2y ? pymax : pymin) + c2s)
                >= -EBIN;

        unsigned long long pmin = ~0ULL;
        unsigned long long mask = __ballot(pass);
        while (mask) {
            const int sl = __builtin_ctzll(mask);
            mask &= mask - 1;
            // cheap affine inside test: 2 LDS reads, 6 VALU + 3 cmp
            const float4 k0 = sface[sl * 7 + 0];
            const float4 k1 = sface[sl * 7 + 1];
            const float g0 = fmaf(k0.x, px, fmaf(k0.y, py, k0.z));
            const float g1 = fmaf(k1.x, px, fmaf(k1.y, py, k1.z));
            const float g2 = k0.w - g0 - g1;
            const bool maybe = (g0 >= -EW) & (g1 >= -EW) & (g2 >= -EW);
            if (!__any(maybe)) continue;
            // z~ window (3rd LDS read only when someone might be inside)
            const float4 kz = sface[sl * 7 + 2];
            const float zt = fmaf(kz.x, px, fmaf(kz.y, py, kz.z));
            const bool need = maybe & (zt < zbf + k1.w);   // k1.w = eps (INF->always)
            if (__any(need)) {
                // ---- bit-exact reference path (round-12 code) ----
                const float4 r0 = sface[sl * 7 + 3];
                const float4 r1 = sface[sl * 7 + 4];
                const float4 r2 = sface[sl * 7 + 5];
                const float4 r3 = sface[sl * 7 + 6];   // den, az, bz, cz
                const float den = r3.x;
                float w0 = r0.x * (py - r0.w) - r0.y * (px - r0.z);
                float w1 = r1.x * (py - r1.w) - r1.y * (px - r1.z);
                float w2 = r2.x * (py - r2.w) - r2.y * (px - r2.z);
                const unsigned ds = __float_as_uint(den) >> 31;
                const bool in0 = (w0 == 0.0f) | ((__float_as_uint(w0) >> 31) == ds);
                const bool in1 = (w1 == 0.0f) | ((__float_as_uint(w1) >> 31) == ds);
                const bool in2 = (w2 == 0.0f) | ((__float_as_uint(w2) >> 31) == ds);
                if (in0 & in1 & in2) {
                    float s0 = w0 / den, s1 = w1 / den, s2 = w2 / den;
                    float z  = s0 * r3.y + s1 * r3.z + s2 * r3.w;
                    if (z > 0.0f) {
                        unsigned long long pk =
                            ((unsigned long long)__float_as_uint(z) << 32) |
                            (unsigned)(f0 + sl);
                        pmin = pmin < pk ? pmin : pk;
                        zbf  = fminf(zbf, z);
                    }
                }
            }
        }
        if (pmin != ~0ULL) atomicMin(&zbest[gp], pmin);
    }
}

// Unpack winner; recompute bary + dists from fdata (reference-rounded values).
__global__ __launch_bounds__(256) void pass2(const float* __restrict__ fdata,
                                             const unsigned long long* __restrict__ zbest,
                                             float* __restrict__ out) {
#pragma clang fp contract(off)
    const int gp = blockIdx.x * 256 + threadIdx.x;
    const int b  = gp >> 14;
    const int p  = gp & (NPIX - 1);
    const int ix = p & (IMG - 1), iy = p >> 7;

    unsigned long long packed = zbest[gp];
    float o_face = -1.0f, o_z = -1.0f, o_b0 = -1.0f, o_b1 = -1.0f,
          o_b2 = -1.0f, o_d = -1.0f;

    if (packed != ~0ULL) {
        const int   idx = (int)(unsigned)(packed & 0xffffffffu);  // face id (==slot)
        const float z   = __uint_as_float((unsigned)(packed >> 32));
        const float px  = 1.0f - (2.0f * (float)ix + 1.0f) / (float)IMG;
        const float py  = 1.0f - (2.0f * (float)iy + 1.0f) / (float)IMG;

        const float4* fd4 = (const float4*)(fdata + (size_t)(b * FP + idx) * 28);
        float4 q0 = fd4[3], q1 = fd4[4], q2 = fd4[5], q3 = fd4[6];
        float den = q3.x;
        float w0 = q0.x * (py - q0.w) - q0.y * (px - q0.z);
        float w1 = q1.x * (py - q1.w) - q1.y * (px - q1.z);
        float w2 = q2.x * (py - q2.w) - q2.y * (px - q2.z);
        float s0 = w0 / den, s1 = w1 / den, s2 = w2 / den;

        // a=(q2.z,q2.w)  b=(q0.z,q0.w)  c=(q1.z,q1.w): reference-rounded coords
        float d2 = fminf(fminf(seg_dist2(px, py, q2.z, q2.w, q0.z, q0.w),
                               seg_dist2(px, py, q0.z, q0.w, q1.z, q1.w)),
                         seg_dist2(px, py, q1.z, q1.w, q2.z, q2.w));
        o_face = (float)idx; o_z = z;
        o_b0 = s0; o_b1 = s1; o_b2 = s2;
        o_d = -d2;
    }

    out[gp]            = o_face;
    out[B * NPIX + gp] = o_z;
    const int bary_base = 2 * B * NPIX;
    out[bary_base + gp * 3 + 0] = o_b0;
    out[bary_base + gp * 3 + 1] = o_b1;
    out[bary_base + gp * 3 + 2] = o_b2;
    out[5 * B * NPIX + gp] = o_d;
}

} // namespace

extern "C" void kernel_launch(void* const* d_in, const int* in_sizes, int n_in,
                              void* d_out, int out_size, void* d_ws, size_t ws_size,
                              hipStream_t stream) {
    const float* verts = (const float*)d_in[0];  // (B,V,3) f32
    const int*   faces = (const int*)d_in[1];    // (F,3) i32
    float* out = (float*)d_out;

    // ws layout: zbest 512KB | fdata B*FP*112B = 448KB
    char* ws = (char*)d_ws;
    unsigned long long* zbest = (unsigned long long*)ws;
    float* fdata = (float*)(ws + (size_t)B * NPIX * 8);

    setup_clear<<<B * NPIX / 256, 256, 0, stream>>>(verts, faces, fdata, zbest);
    // 1024 blocks x 8 waves = 8192 waves, all co-resident (32 waves/CU);
    // block = (chunk, image, lattice-slice), 16 tiles via LDS ticket.
    rast<<<1024, 512, 0, stream>>>(fdata, zbest);
    pass2<<<B * NPIX / 256, 256, 0, stream>>>(fdata, zbest, out);
}